// Round 3
// baseline (275.279 us; speedup 1.0000x reference)
//
#include <hip/hip_runtime.h>
#include <hip/hip_bf16.h>

// B=1024, S=128, E=256, H=2, DH=128.  v/Wv/bv are dead in the reference.
// out = softmax((q@Wq+bq)/16 [s, h,:] . (k@Wk+bk)[:, h,:] + (mask==0)) @ Wo + bo
#define NB 1024
#define NS 128
#define NE 256

typedef __attribute__((ext_vector_type(8))) short bf16x8;
typedef __attribute__((ext_vector_type(4))) float f32x4;

__device__ __forceinline__ unsigned short f2bf(float x) {
  unsigned int u = __float_as_uint(x);
  u = (u + 0x7fffu + ((u >> 16) & 1u)) >> 16;   // RNE
  return (unsigned short)u;
}

// WT[n][k] = W[k][n]  (bf16) -- B-operand wants [N][K] contiguous-K rows.
__global__ void prep_weights(const float* __restrict__ Wq,
                             const float* __restrict__ Wk,
                             const float* __restrict__ Wo,
                             short* __restrict__ WqT,
                             short* __restrict__ WkT,
                             short* __restrict__ WoT) {
  int idx = blockIdx.x * blockDim.x + threadIdx.x;  // = n*256 + k
  int n = idx >> 8;
  int kk = idx & 255;
  WqT[idx] = (short)f2bf(Wq[kk * NE + n]);
  WkT[idx] = (short)f2bf(Wk[kk * NE + n]);
  WoT[idx] = (short)f2bf(Wo[kk * NE + n]);
}

// 128x256 @ 256x256: A from LDS (bf16, 512B rows, XOR-swizzled), B from
// global [N][K] bf16 (L2-hot weights). 16 waves in a 4x4 grid; each wave
// owns 2 row-tiles x 4 col-tiles of 16x16.
__device__ __forceinline__ void gemm_2x4(const char* __restrict__ ldsA,
                                         const short* __restrict__ BT,
                                         int wr, int wc, int cl, int c4,
                                         f32x4 acc[2][4]) {
  #pragma unroll
  for (int ks = 0; ks < 8; ++ks) {
    const int kel = ks * 32 + 8 * c4;            // lane's 8 contiguous k elems
    bf16x8 a[2], bb[4];
    #pragma unroll
    for (int mi = 0; mi < 2; ++mi) {
      int row = wr * 32 + mi * 16 + cl;
      a[mi] = *reinterpret_cast<const bf16x8*>(
          ldsA + row * 512 + ((kel * 2) ^ ((row & 7) << 4)));
    }
    #pragma unroll
    for (int ni = 0; ni < 4; ++ni) {
      int col = wc * 64 + ni * 16 + cl;
      bb[ni] = *reinterpret_cast<const bf16x8*>(BT + col * 256 + kel);
    }
    #pragma unroll
    for (int mi = 0; mi < 2; ++mi)
      #pragma unroll
      for (int ni = 0; ni < 4; ++ni)
        acc[mi][ni] = __builtin_amdgcn_mfma_f32_16x16x32_bf16(
            a[mi], bb[ni], acc[mi][ni], 0, 0, 0);
  }
}

__global__ __launch_bounds__(1024, 4)
void fused_attn(const float* __restrict__ q,
                const float* __restrict__ kin,
                const int* __restrict__ am,
                const float* __restrict__ bq,
                const float* __restrict__ bk,
                const float* __restrict__ bo,
                const short* __restrict__ WqT,
                const short* __restrict__ WkT,
                const short* __restrict__ WoT,
                float* __restrict__ out) {
  extern __shared__ char lds[];
  char* ST = lds;            // 64KB: staged k -> staged q -> qp -> probs
  char* KT = lds + 65536;    // 64KB: kpT [h][j][seq], swizzled 256B rows

  const int t = threadIdx.x;
  const int lane = t & 63;
  const int wid = t >> 6;     // 16 waves
  const int cl = lane & 15;
  const int c4 = lane >> 4;
  const int wr = wid >> 2;    // 0..3
  const int wc = wid & 3;     // 0..3
  const int b = blockIdx.x;

  const float* qb = q + (size_t)b * (NS * NE);
  const float* kb = kin + (size_t)b * (NS * NE);

  f32x4 acc[2][4];

  // ---- P1: stage K -> ST (bf16, swizzled); prefetch q into registers ----
  float4 qv[8];
  {
    const float4* k4 = reinterpret_cast<const float4*>(kb);
    const float4* q4 = reinterpret_cast<const float4*>(qb);
    #pragma unroll
    for (int i = 0; i < 8; ++i) {
      int idx = t + i * 1024;                    // 8192 float4 total
      float4 v = k4[idx];
      qv[i] = q4[idx];                           // in flight during kp gemm drain
      int row = idx >> 6;                        // 64 float4 per row
      int colb = (idx & 63) << 3;                // byte offset within row
      ushort4 u;
      u.x = f2bf(v.x); u.y = f2bf(v.y); u.z = f2bf(v.z); u.w = f2bf(v.w);
      *reinterpret_cast<ushort4*>(ST + row * 512 + (colb ^ ((row & 7) << 4))) = u;
    }
  }
  __syncthreads();

  // ---- P2: kp = k @ Wk + bk ; store transposed per head into KT ----
  #pragma unroll
  for (int mi = 0; mi < 2; ++mi)
    #pragma unroll
    for (int ni = 0; ni < 4; ++ni) acc[mi][ni] = (f32x4){0.f, 0.f, 0.f, 0.f};
  gemm_2x4(ST, WkT, wr, wc, cl, c4, acc);
  #pragma unroll
  for (int mi = 0; mi < 2; ++mi)
    #pragma unroll
    for (int ni = 0; ni < 4; ++ni) {
      int ce = wc * 64 + ni * 16 + cl;           // E column
      float bkv = bk[ce];
      int h = ce >> 7, j = ce & 127;
      int seq0 = wr * 32 + mi * 16 + c4 * 4;     // 4 consecutive seq -> 8B pack
      ushort4 u;
      u.x = f2bf(acc[mi][ni][0] + bkv);
      u.y = f2bf(acc[mi][ni][1] + bkv);
      u.z = f2bf(acc[mi][ni][2] + bkv);
      u.w = f2bf(acc[mi][ni][3] + bkv);
      *reinterpret_cast<ushort4*>(
          KT + h * 32768 + j * 256 + ((seq0 * 2) ^ ((j & 7) << 4))) = u;
    }
  __syncthreads();   // ST reads done, KT fully written

  // ---- P3: write prefetched q over ST ----
  #pragma unroll
  for (int i = 0; i < 8; ++i) {
    int idx = t + i * 1024;
    int row = idx >> 6;
    int colb = (idx & 63) << 3;
    ushort4 u;
    u.x = f2bf(qv[i].x); u.y = f2bf(qv[i].y);
    u.z = f2bf(qv[i].z); u.w = f2bf(qv[i].w);
    *reinterpret_cast<ushort4*>(ST + row * 512 + (colb ^ ((row & 7) << 4))) = u;
  }
  __syncthreads();

  // ---- P4: qp = (q @ Wq + bq) * (1/16); write bf16 back over ST ----
  #pragma unroll
  for (int mi = 0; mi < 2; ++mi)
    #pragma unroll
    for (int ni = 0; ni < 4; ++ni) acc[mi][ni] = (f32x4){0.f, 0.f, 0.f, 0.f};
  gemm_2x4(ST, WqT, wr, wc, cl, c4, acc);
  __syncthreads();   // every wave done READING staged q before overwrite
  #pragma unroll
  for (int mi = 0; mi < 2; ++mi)
    #pragma unroll
    for (int ni = 0; ni < 4; ++ni) {
      int ce = wc * 64 + ni * 16 + cl;
      float bqv = bq[ce];
      int ceb = ce * 2;
      #pragma unroll
      for (int r = 0; r < 4; ++r) {
        int seq = wr * 32 + mi * 16 + c4 * 4 + r;
        *reinterpret_cast<unsigned short*>(
            ST + seq * 512 + (ceb ^ ((seq & 7) << 4))) =
            f2bf((acc[mi][ni][r] + bqv) * 0.0625f);
      }
    }
  __syncthreads();

  // ---- P5: scores -> softmax -> probs. Head-parallel: wave = (h, row-tile).
  // Wave reads ONLY its own rows x its own head's col-half of ST, and writes
  // the same region -> no barrier inside the phase.
  {
    const int h = wid >> 3;    // 0..1
    const int rt = wid & 7;    // 0..7 row tile
    f32x4 sacc[8];
    #pragma unroll
    for (int ni = 0; ni < 8; ++ni) sacc[ni] = (f32x4){0.f, 0.f, 0.f, 0.f};
    const int arow = rt * 16 + cl;
    #pragma unroll
    for (int ks = 0; ks < 4; ++ks) {
      int kel = h * 128 + ks * 32 + 8 * c4;      // col in qp (A k-index)
      bf16x8 a = *reinterpret_cast<const bf16x8*>(
          ST + arow * 512 + ((kel * 2) ^ ((arow & 7) << 4)));
      int kb2 = (ks * 32 + 8 * c4) * 2;          // byte offset in KT row (seq)
      #pragma unroll
      for (int ni = 0; ni < 8; ++ni) {
        int jr = ni * 16 + cl;                   // dh j (B n-index)
        bf16x8 bbv = *reinterpret_cast<const bf16x8*>(
            KT + h * 32768 + jr * 256 + (kb2 ^ ((jr & 7) << 4)));
        sacc[ni] = __builtin_amdgcn_mfma_f32_16x16x32_bf16(
            a, bbv, sacc[ni], 0, 0, 0);
      }
    }
    // additive mask: +1.0 where attention_mask[b][j]==0 (same for both heads)
    float madd[8];
    #pragma unroll
    for (int ni = 0; ni < 8; ++ni)
      madd[ni] = (am[b * NS + ni * 16 + cl] == 0) ? 1.0f : 0.0f;
    // wave-parallel softmax along j: in-lane over 8 tiles, then shfl_xor
    // across the 16 lanes (cl) sharing each row.
    #pragma unroll
    for (int r = 0; r < 4; ++r) {
      float m = -1e30f;
      #pragma unroll
      for (int ni = 0; ni < 8; ++ni) m = fmaxf(m, sacc[ni][r] + madd[ni]);
      #pragma unroll
      for (int d = 1; d < 16; d <<= 1) m = fmaxf(m, __shfl_xor(m, d, 64));
      float s = 0.f;
      #pragma unroll
      for (int ni = 0; ni < 8; ++ni) {
        float e = __expf(sacc[ni][r] + madd[ni] - m);
        sacc[ni][r] = e;
        s += e;
      }
      #pragma unroll
      for (int d = 1; d < 16; d <<= 1) s += __shfl_xor(s, d, 64);
      float rinv = 1.0f / s;
      #pragma unroll
      for (int ni = 0; ni < 8; ++ni) sacc[ni][r] *= rinv;
    }
    // write probs bf16: ST[row][h*128 + j] (own rows, own head-half only)
    #pragma unroll
    for (int ni = 0; ni < 8; ++ni)
      #pragma unroll
      for (int r = 0; r < 4; ++r) {
        int row = rt * 16 + c4 * 4 + r;
        int ceb = (h * 128 + ni * 16 + cl) * 2;
        *reinterpret_cast<unsigned short*>(
            ST + row * 512 + (ceb ^ ((row & 7) << 4))) = f2bf(sacc[ni][r]);
      }
  }
  __syncthreads();

  // ---- P6: out = P @ Wo + bo ----
  #pragma unroll
  for (int mi = 0; mi < 2; ++mi)
    #pragma unroll
    for (int ni = 0; ni < 4; ++ni) acc[mi][ni] = (f32x4){0.f, 0.f, 0.f, 0.f};
  gemm_2x4(ST, WoT, wr, wc, cl, c4, acc);
  float* ob = out + (size_t)b * (NS * NE);
  #pragma unroll
  for (int mi = 0; mi < 2; ++mi)
    #pragma unroll
    for (int ni = 0; ni < 4; ++ni) {
      int ce = wc * 64 + ni * 16 + cl;
      float bov = bo[ce];
      #pragma unroll
      for (int r = 0; r < 4; ++r) {
        int seq = wr * 32 + mi * 16 + c4 * 4 + r;
        ob[seq * NE + ce] = acc[mi][ni][r] + bov;
      }
    }
}

extern "C" void kernel_launch(void* const* d_in, const int* in_sizes, int n_in,
                              void* d_out, int out_size, void* d_ws, size_t ws_size,
                              hipStream_t stream) {
  const float* q  = (const float*)d_in[0];
  const float* k  = (const float*)d_in[1];
  // d_in[2] = v : dead in the reference, never touched
  const int*   am = (const int*)d_in[3];
  const float* Wq = (const float*)d_in[4];
  const float* bq = (const float*)d_in[5];
  const float* Wk = (const float*)d_in[6];
  const float* bk = (const float*)d_in[7];
  // d_in[8] = Wv, d_in[9] = bv : dead
  const float* Wo = (const float*)d_in[10];
  const float* bo = (const float*)d_in[11];
  float* out = (float*)d_out;

  // workspace: 3 x 256x256 bf16 transposed weights = 384KB
  short* WqT = (short*)d_ws;
  short* WkT = WqT + NE * NE;
  short* WoT = WkT + NE * NE;

  prep_weights<<<NE * NE / 256, 256, 0, stream>>>(Wq, Wk, Wo, WqT, WkT, WoT);

  (void)hipFuncSetAttribute((const void*)fused_attn,
                            hipFuncAttributeMaxDynamicSharedMemorySize, 131072);
  fused_attn<<<NB, 1024, 131072, stream>>>(q, k, am, bq, bk, bo,
                                           WqT, WkT, WoT, out);
}

// Round 4
// 257.694 us; speedup vs baseline: 1.0682x; 1.0682x over previous
//
#include <hip/hip_runtime.h>
#include <hip/hip_bf16.h>

// B=1024, S=128, E=256, H=2, DH=128.  v/Wv/bv are dead in the reference.
// out = softmax((q@Wq+bq)/16 [s, h,:] . (k@Wk+bk)[:, h,:] + (mask==0)) @ Wo + bo
#define NB 1024
#define NS 128
#define NE 256

typedef __attribute__((ext_vector_type(8))) short bf16x8;
typedef __attribute__((ext_vector_type(4))) float f32x4;

__device__ __forceinline__ unsigned short f2bf(float x) {
  unsigned int u = __float_as_uint(x);
  u = (u + 0x7fffu + ((u >> 16) & 1u)) >> 16;   // RNE
  return (unsigned short)u;
}

// WT[n][k] = W[k][n]  (bf16) -- B-operand wants [N][K] contiguous-K rows.
__global__ void prep_weights(const float* __restrict__ Wq,
                             const float* __restrict__ Wk,
                             const float* __restrict__ Wo,
                             short* __restrict__ WqT,
                             short* __restrict__ WkT,
                             short* __restrict__ WoT) {
  int idx = blockIdx.x * blockDim.x + threadIdx.x;  // = n*256 + k
  int n = idx >> 8;
  int kk = idx & 255;
  WqT[idx] = (short)f2bf(Wq[kk * NE + n]);
  WkT[idx] = (short)f2bf(Wk[kk * NE + n]);
  WoT[idx] = (short)f2bf(Wo[kk * NE + n]);
}

// Stage a 128x256 f32 global tile into LDS as bf16, rows of 512B,
// XOR-swizzled: byte_in_row ^= (row&7)<<4.
__device__ __forceinline__ void stage_tile(const float* __restrict__ src,
                                           char* __restrict__ dst, int t) {
  #pragma unroll
  for (int i = 0; i < 16; ++i) {
    int idx = t + i * 512;                       // float4 index, coalesced
    float4 v = reinterpret_cast<const float4*>(src)[idx];
    int row = idx >> 6;                          // 64 float4 per row
    int colb = (idx & 63) << 3;                  // byte offset within row
    ushort4 u;
    u.x = f2bf(v.x); u.y = f2bf(v.y); u.z = f2bf(v.z); u.w = f2bf(v.w);
    *reinterpret_cast<ushort4*>(dst + row * 512 + (colb ^ ((row & 7) << 4))) = u;
  }
}

// 128x256 = A(128x256 LDS swizzled bf16) @ B(256x256 global bf16 [N][K]).
// 8 waves, 2x4 grid; wave owns 4 row-tiles x 4 col-tiles of 16x16.
__device__ __forceinline__ void gemm_8x16(const char* __restrict__ ldsA,
                                          const short* __restrict__ BT,
                                          int wr, int wc, int cl, int c4,
                                          f32x4 acc[4][4]) {
  #pragma unroll
  for (int ks = 0; ks < 8; ++ks) {
    const int kel = ks * 32 + 8 * c4;            // lane's 8 contiguous k elems
    bf16x8 a[4], bb[4];
    #pragma unroll
    for (int mi = 0; mi < 4; ++mi) {
      int row = wr * 64 + mi * 16 + cl;
      a[mi] = *reinterpret_cast<const bf16x8*>(
          ldsA + row * 512 + ((kel * 2) ^ ((row & 7) << 4)));
    }
    #pragma unroll
    for (int ni = 0; ni < 4; ++ni) {
      int col = wc * 64 + ni * 16 + cl;
      bb[ni] = *reinterpret_cast<const bf16x8*>(BT + col * 256 + kel);
    }
    #pragma unroll
    for (int mi = 0; mi < 4; ++mi)
      #pragma unroll
      for (int ni = 0; ni < 4; ++ni)
        acc[mi][ni] = __builtin_amdgcn_mfma_f32_16x16x32_bf16(
            a[mi], bb[ni], acc[mi][ni], 0, 0, 0);
  }
}

// ======================= split path, kernel 1 =======================
// blockIdx: b = >>1, src = &1.  src==0: KPT[b][e][m] = (k@Wk+bk)^T  (bf16)
//                               src==1: QP[b] = (q@Wq+bq)/16, swizzled image
__global__ __launch_bounds__(512, 4)
void proj_qk(const float* __restrict__ q,
             const float* __restrict__ kin,
             const float* __restrict__ bq,
             const float* __restrict__ bk,
             const short* __restrict__ WqT,
             const short* __restrict__ WkT,
             short* __restrict__ QP,
             short* __restrict__ KPT) {
  extern __shared__ char ST[];   // 64KB
  const int t = threadIdx.x;
  const int lane = t & 63;
  const int wid = t >> 6;        // 8 waves
  const int cl = lane & 15;
  const int c4 = lane >> 4;
  const int b = blockIdx.x >> 1;

  if ((blockIdx.x & 1) == 0) {
    // ---- kpT: C[e][m] = sum_kk WkT[e][kk] * k[m][kk] ----
    stage_tile(kin + (size_t)b * (NS * NE), ST, t);
    __syncthreads();
    const int we = wid >> 1;     // 0..3 : e-tiles we*4..+4
    const int wm = wid & 1;      // 0..1 : m-tiles wm*4..+4
    f32x4 acc[4][4];
    #pragma unroll
    for (int ei = 0; ei < 4; ++ei)
      #pragma unroll
      for (int mi = 0; mi < 4; ++mi) acc[ei][mi] = (f32x4){0.f, 0.f, 0.f, 0.f};
    #pragma unroll
    for (int ks = 0; ks < 8; ++ks) {
      const int kel = ks * 32 + 8 * c4;
      bf16x8 a[4], bb[4];
      #pragma unroll
      for (int ei = 0; ei < 4; ++ei) {
        int er = we * 64 + ei * 16 + cl;
        a[ei] = *reinterpret_cast<const bf16x8*>(WkT + er * 256 + kel);
      }
      #pragma unroll
      for (int mi = 0; mi < 4; ++mi) {
        int mr = wm * 64 + mi * 16 + cl;
        bb[mi] = *reinterpret_cast<const bf16x8*>(
            ST + mr * 512 + ((kel * 2) ^ ((mr & 7) << 4)));
      }
      #pragma unroll
      for (int ei = 0; ei < 4; ++ei)
        #pragma unroll
        for (int mi = 0; mi < 4; ++mi)
          acc[ei][mi] = __builtin_amdgcn_mfma_f32_16x16x32_bf16(
              a[ei], bb[mi], acc[ei][mi], 0, 0, 0);
    }
    short* kp = KPT + (size_t)b * (NE * NS);
    #pragma unroll
    for (int ei = 0; ei < 4; ++ei)
      #pragma unroll
      for (int r = 0; r < 4; ++r) {
        int e = we * 64 + ei * 16 + c4 * 4 + r;
        float bkv = bk[e];
        #pragma unroll
        for (int mi = 0; mi < 4; ++mi) {
          int m = wm * 64 + mi * 16 + cl;
          kp[e * NS + m] = (short)f2bf(acc[ei][mi][r] + bkv);
        }
      }
  } else {
    // ---- qp = (q@Wq+bq)/16 -> swizzled bf16 image (kernel2 copies raw) ----
    stage_tile(q + (size_t)b * (NS * NE), ST, t);
    __syncthreads();
    const int wr = wid >> 2, wc = wid & 3;
    f32x4 acc[4][4];
    #pragma unroll
    for (int mi = 0; mi < 4; ++mi)
      #pragma unroll
      for (int ni = 0; ni < 4; ++ni) acc[mi][ni] = (f32x4){0.f, 0.f, 0.f, 0.f};
    gemm_8x16(ST, WqT, wr, wc, cl, c4, acc);
    char* qp = (char*)QP + (size_t)b * 65536;
    #pragma unroll
    for (int mi = 0; mi < 4; ++mi)
      #pragma unroll
      for (int ni = 0; ni < 4; ++ni) {
        int ce = wc * 64 + ni * 16 + cl;
        float bqv = bq[ce];
        #pragma unroll
        for (int r = 0; r < 4; ++r) {
          int seq = wr * 64 + mi * 16 + c4 * 4 + r;
          *reinterpret_cast<unsigned short*>(
              qp + seq * 512 + ((ce * 2) ^ ((seq & 7) << 4))) =
              f2bf((acc[mi][ni][r] + bqv) * 0.0625f);
        }
      }
  }
}

// ======================= split path, kernel 2 =======================
__global__ __launch_bounds__(512, 4)
void attn_out(const short* __restrict__ QP,
              const short* __restrict__ KPT,
              const int* __restrict__ am,
              const float* __restrict__ bo,
              const short* __restrict__ WoT,
              float* __restrict__ out) {
  extern __shared__ char ST[];   // 64KB: qp image -> probs (in place)
  const int t = threadIdx.x;
  const int lane = t & 63;
  const int wid = t >> 6;
  const int cl = lane & 15;
  const int c4 = lane >> 4;
  const int b = blockIdx.x;

  // P0: copy pre-swizzled qp image into LDS (bit-exact, coalesced 16B)
  {
    const int4* src = reinterpret_cast<const int4*>((const char*)QP + (size_t)b * 65536);
    int4* dst = reinterpret_cast<int4*>(ST);
    #pragma unroll
    for (int i = 0; i < 8; ++i) dst[t + i * 512] = src[t + i * 512];
  }
  __syncthreads();

  // P1: scores -> softmax -> probs.  Wave owns seq rows [wid*16, +16), both heads.
  {
    const short* kp = KPT + (size_t)b * (NE * NS);
    f32x4 sacc[2][8];
    #pragma unroll
    for (int h = 0; h < 2; ++h)
      #pragma unroll
      for (int ni = 0; ni < 8; ++ni) sacc[h][ni] = (f32x4){0.f, 0.f, 0.f, 0.f};
    const int arow = wid * 16 + cl;
    #pragma unroll
    for (int h = 0; h < 2; ++h) {
      #pragma unroll
      for (int ks = 0; ks < 4; ++ks) {
        int kel = h * 128 + ks * 32 + 8 * c4;    // qp col (A k-index)
        bf16x8 a = *reinterpret_cast<const bf16x8*>(
            ST + arow * 512 + ((kel * 2) ^ ((arow & 7) << 4)));
        int mel = ks * 32 + 8 * c4;              // kpT col (B k-index = seq m)
        #pragma unroll
        for (int ni = 0; ni < 8; ++ni) {
          int jr = ni * 16 + cl;                 // dh j (B n-index)
          bf16x8 bbv = *reinterpret_cast<const bf16x8*>(
              kp + (h * 128 + jr) * NS + mel);
          sacc[h][ni] = __builtin_amdgcn_mfma_f32_16x16x32_bf16(
              a, bbv, sacc[h][ni], 0, 0, 0);
        }
      }
    }
    // additive mask: +1.0 where attention_mask[b][j]==0 (both heads)
    float madd[8];
    #pragma unroll
    for (int ni = 0; ni < 8; ++ni)
      madd[ni] = (am[b * NS + ni * 16 + cl] == 0) ? 1.0f : 0.0f;
    #pragma unroll
    for (int h = 0; h < 2; ++h) {
      #pragma unroll
      for (int r = 0; r < 4; ++r) {
        float m = -1e30f;
        #pragma unroll
        for (int ni = 0; ni < 8; ++ni) m = fmaxf(m, sacc[h][ni][r] + madd[ni]);
        #pragma unroll
        for (int d = 1; d < 16; d <<= 1) m = fmaxf(m, __shfl_xor(m, d, 64));
        float s = 0.f;
        #pragma unroll
        for (int ni = 0; ni < 8; ++ni) {
          float e = __expf(sacc[h][ni][r] + madd[ni] - m);
          sacc[h][ni][r] = e;
          s += e;
        }
        #pragma unroll
        for (int d = 1; d < 16; d <<= 1) s += __shfl_xor(s, d, 64);
        float rinv = 1.0f / s;
        #pragma unroll
        for (int ni = 0; ni < 8; ++ni) sacc[h][ni][r] *= rinv;
      }
    }
    // probs bf16 over qp image (own rows only -> no barrier needed here)
    #pragma unroll
    for (int h = 0; h < 2; ++h)
      #pragma unroll
      for (int ni = 0; ni < 8; ++ni)
        #pragma unroll
        for (int r = 0; r < 4; ++r) {
          int row = wid * 16 + c4 * 4 + r;
          int ceb = (h * 128 + ni * 16 + cl) * 2;
          *reinterpret_cast<unsigned short*>(
              ST + row * 512 + (ceb ^ ((row & 7) << 4))) = f2bf(sacc[h][ni][r]);
        }
  }
  __syncthreads();

  // P2: out = P @ Wo + bo
  const int wr = wid >> 2, wc = wid & 3;
  f32x4 acc[4][4];
  #pragma unroll
  for (int mi = 0; mi < 4; ++mi)
    #pragma unroll
    for (int ni = 0; ni < 4; ++ni) acc[mi][ni] = (f32x4){0.f, 0.f, 0.f, 0.f};
  gemm_8x16(ST, WoT, wr, wc, cl, c4, acc);
  float* ob = out + (size_t)b * (NS * NE);
  #pragma unroll
  for (int mi = 0; mi < 4; ++mi)
    #pragma unroll
    for (int ni = 0; ni < 4; ++ni) {
      int ce = wc * 64 + ni * 16 + cl;
      float bov = bo[ce];
      #pragma unroll
      for (int r = 0; r < 4; ++r) {
        int seq = wr * 64 + mi * 16 + c4 * 4 + r;
        ob[seq * NE + ce] = acc[mi][ni][r] + bov;
      }
    }
}

// ============== fallback: proven R2 fused kernel (194us) ==============
__global__ __launch_bounds__(512, 2)
void fused_attn(const float* __restrict__ q,
                const float* __restrict__ kin,
                const int* __restrict__ am,
                const float* __restrict__ bq,
                const float* __restrict__ bk,
                const float* __restrict__ bo,
                const short* __restrict__ WqT,
                const short* __restrict__ WkT,
                const short* __restrict__ WoT,
                float* __restrict__ out) {
  extern __shared__ char lds[];
  char* stA = lds;
  char* kpT = lds + 65536;
  const int t = threadIdx.x;
  const int lane = t & 63;
  const int wid = t >> 6;
  const int cl = lane & 15;
  const int c4 = lane >> 4;
  const int wr = wid >> 2;
  const int wc = wid & 3;
  const int b = blockIdx.x;
  f32x4 acc[4][4];

  stage_tile(kin + (size_t)b * (NS * NE), stA, t);
  __syncthreads();
  #pragma unroll
  for (int mi = 0; mi < 4; ++mi)
    #pragma unroll
    for (int ni = 0; ni < 4; ++ni) acc[mi][ni] = (f32x4){0.f, 0.f, 0.f, 0.f};
  gemm_8x16(stA, WkT, wr, wc, cl, c4, acc);
  #pragma unroll
  for (int mi = 0; mi < 4; ++mi)
    #pragma unroll
    for (int ni = 0; ni < 4; ++ni) {
      int ce = wc * 64 + ni * 16 + cl;
      float bkv = bk[ce];
      int h = ce >> 7, j = ce & 127;
      char* base = kpT + h * 32768 + j * 256;
      int sw = (j & 7) << 4;
      #pragma unroll
      for (int r = 0; r < 4; ++r) {
        int seq = wr * 64 + mi * 16 + c4 * 4 + r;
        *reinterpret_cast<unsigned short*>(base + ((seq * 2) ^ sw)) =
            f2bf(acc[mi][ni][r] + bkv);
      }
    }
  __syncthreads();
  stage_tile(q + (size_t)b * (NS * NE), stA, t);
  __syncthreads();
  #pragma unroll
  for (int mi = 0; mi < 4; ++mi)
    #pragma unroll
    for (int ni = 0; ni < 4; ++ni) acc[mi][ni] = (f32x4){0.f, 0.f, 0.f, 0.f};
  gemm_8x16(stA, WqT, wr, wc, cl, c4, acc);
  __syncthreads();
  #pragma unroll
  for (int mi = 0; mi < 4; ++mi)
    #pragma unroll
    for (int ni = 0; ni < 4; ++ni) {
      int ce = wc * 64 + ni * 16 + cl;
      float bqv = bq[ce];
      int ceb = ce * 2;
      #pragma unroll
      for (int r = 0; r < 4; ++r) {
        int seq = wr * 64 + mi * 16 + c4 * 4 + r;
        *reinterpret_cast<unsigned short*>(
            stA + seq * 512 + (ceb ^ ((seq & 7) << 4))) =
            f2bf((acc[mi][ni][r] + bqv) * 0.0625f);
      }
    }
  __syncthreads();
  {
    f32x4 sacc[2][8];
    #pragma unroll
    for (int h = 0; h < 2; ++h)
      #pragma unroll
      for (int ni = 0; ni < 8; ++ni) sacc[h][ni] = (f32x4){0.f, 0.f, 0.f, 0.f};
    const int arow = wid * 16 + cl;
    #pragma unroll
    for (int h = 0; h < 2; ++h) {
      #pragma unroll
      for (int ks = 0; ks < 4; ++ks) {
        int kel = h * 128 + ks * 32 + 8 * c4;
        bf16x8 a = *reinterpret_cast<const bf16x8*>(
            stA + arow * 512 + ((kel * 2) ^ ((arow & 7) << 4)));
        int kb = (ks * 32 + 8 * c4) * 2;
        #pragma unroll
        for (int ni = 0; ni < 8; ++ni) {
          int jr = ni * 16 + cl;
          bf16x8 bbv = *reinterpret_cast<const bf16x8*>(
              kpT + h * 32768 + jr * 256 + (kb ^ ((jr & 7) << 4)));
          sacc[h][ni] = __builtin_amdgcn_mfma_f32_16x16x32_bf16(
              a, bbv, sacc[h][ni], 0, 0, 0);
        }
      }
    }
    float madd[8];
    #pragma unroll
    for (int ni = 0; ni < 8; ++ni)
      madd[ni] = (am[b * NS + ni * 16 + cl] == 0) ? 1.0f : 0.0f;
    #pragma unroll
    for (int h = 0; h < 2; ++h) {
      #pragma unroll
      for (int r = 0; r < 4; ++r) {
        float m = -1e30f;
        #pragma unroll
        for (int ni = 0; ni < 8; ++ni) m = fmaxf(m, sacc[h][ni][r] + madd[ni]);
        #pragma unroll
        for (int d = 1; d < 16; d <<= 1) m = fmaxf(m, __shfl_xor(m, d, 64));
        float s = 0.f;
        #pragma unroll
        for (int ni = 0; ni < 8; ++ni) {
          float e = __expf(sacc[h][ni][r] + madd[ni] - m);
          sacc[h][ni][r] = e;
          s += e;
        }
        #pragma unroll
        for (int d = 1; d < 16; d <<= 1) s += __shfl_xor(s, d, 64);
        float rinv = 1.0f / s;
        #pragma unroll
        for (int ni = 0; ni < 8; ++ni) sacc[h][ni][r] *= rinv;
      }
    }
    #pragma unroll
    for (int h = 0; h < 2; ++h)
      #pragma unroll
      for (int ni = 0; ni < 8; ++ni)
        #pragma unroll
        for (int r = 0; r < 4; ++r) {
          int seq = wid * 16 + c4 * 4 + r;
          int ceb = (h * 128 + ni * 16 + cl) * 2;
          *reinterpret_cast<unsigned short*>(
              stA + seq * 512 + (ceb ^ ((seq & 7) << 4))) = f2bf(sacc[h][ni][r]);
        }
  }
  __syncthreads();
  #pragma unroll
  for (int mi = 0; mi < 4; ++mi)
    #pragma unroll
    for (int ni = 0; ni < 4; ++ni) acc[mi][ni] = (f32x4){0.f, 0.f, 0.f, 0.f};
  gemm_8x16(stA, WoT, wr, wc, cl, c4, acc);
  float* ob = out + (size_t)b * (NS * NE);
  #pragma unroll
  for (int mi = 0; mi < 4; ++mi)
    #pragma unroll
    for (int ni = 0; ni < 4; ++ni) {
      int ce = wc * 64 + ni * 16 + cl;
      float bov = bo[ce];
      #pragma unroll
      for (int r = 0; r < 4; ++r) {
        int seq = wr * 64 + mi * 16 + c4 * 4 + r;
        ob[seq * NE + ce] = acc[mi][ni][r] + bov;
      }
    }
}

extern "C" void kernel_launch(void* const* d_in, const int* in_sizes, int n_in,
                              void* d_out, int out_size, void* d_ws, size_t ws_size,
                              hipStream_t stream) {
  const float* q  = (const float*)d_in[0];
  const float* k  = (const float*)d_in[1];
  // d_in[2] = v : dead in the reference, never touched
  const int*   am = (const int*)d_in[3];
  const float* Wq = (const float*)d_in[4];
  const float* bq = (const float*)d_in[5];
  const float* Wk = (const float*)d_in[6];
  const float* bk = (const float*)d_in[7];
  // d_in[8] = Wv, d_in[9] = bv : dead
  const float* Wo = (const float*)d_in[10];
  const float* bo = (const float*)d_in[11];
  float* out = (float*)d_out;

  // workspace layout: WqT/WkT/WoT (384KB) then QP (64MB) then KPT (64MB)
  short* WqT = (short*)d_ws;
  short* WkT = WqT + NE * NE;
  short* WoT = WkT + NE * NE;
  short* QP  = WoT + NE * NE;
  short* KPT = QP + (size_t)NB * NS * NE;

  prep_weights<<<NE * NE / 256, 256, 0, stream>>>(Wq, Wk, Wo, WqT, WkT, WoT);

  const size_t need = 3ULL * NE * NE * 2 + 2ULL * NB * NS * NE * 2;
  if (ws_size >= need) {
    proj_qk<<<2 * NB, 512, 65536, stream>>>(q, k, bq, bk, WqT, WkT, QP, KPT);
    attn_out<<<NB, 512, 65536, stream>>>(QP, KPT, am, bo, WoT, out);
  } else {
    (void)hipFuncSetAttribute((const void*)fused_attn,
                              hipFuncAttributeMaxDynamicSharedMemorySize, 131072);
    fused_attn<<<NB, 512, 131072, stream>>>(q, k, am, bq, bk, bo,
                                            WqT, WkT, WoT, out);
  }
}